// Round 4
// baseline (3665.301 us; speedup 1.0000x reference)
//
#include <hip/hip_runtime.h>
#include <hip/hip_bf16.h>
#include <math.h>

typedef __hip_bfloat16 bf16;
__device__ __forceinline__ float toF(float v){ return v; }
__device__ __forceinline__ float toF(bf16 v){ return __bfloat162float(v); }
__device__ __forceinline__ bf16 f2bf(float v){ return __float2bfloat16(v); }

#define D_    300
#define H_    5
#define NB    64
#define LL    1024
#define KK    64
#define ETXT  2048
#define EIMG  512
#define MAXDEG 128
#define KC    1504   // padded K for GEMM (5*300 -> 1504 = 47*32)
#define BN2   320    // output cols per block (300 padded)
#define BM2   64     // rows per block

typedef __attribute__((ext_vector_type(8))) short short8;
typedef __attribute__((ext_vector_type(4))) float f32x4;

// Mask storage modes: 0 = 4-byte word (int32/f32), 1 = 2-byte, 2 = 1-byte (bool), 3 = 8-byte.
__device__ __forceinline__ int read_mask(const void* p, int i, int mode) {
  switch (mode) {
    case 1: return ((const unsigned short*)p)[i] != 0;
    case 2: return ((const unsigned char*)p)[i] != 0;
    case 3: { const unsigned int* w = (const unsigned int*)p;
              return (w[2*i] | w[2*i+1]) != 0; }
    default: return ((const unsigned int*)p)[i] != 0;
  }
}

__global__ void k_detect(const unsigned int* __restrict__ w, int nwords,
                         int* __restrict__ mode) {
  __shared__ unsigned int se[256], so[256];
  unsigned int oe = 0, oo = 0;
  for (int i = threadIdx.x; i < nwords; i += 256) {
    unsigned int v = w[i];
    if (i & 1) oo |= v; else oe |= v;
  }
  se[threadIdx.x] = oe; so[threadIdx.x] = oo;
  __syncthreads();
  for (int s = 128; s; s >>= 1) {
    if (threadIdx.x < s) { se[threadIdx.x] |= se[threadIdx.x+s]; so[threadIdx.x] |= so[threadIdx.x+s]; }
    __syncthreads();
  }
  if (threadIdx.x == 0) {
    unsigned int O = se[0] | so[0];
    int m = 0;
    if (O == 0u) m = 0;
    else if ((O & 0xFFFFu) == 0x3F80u) m = 1;
    else if ((O >> 16) == 0x3F80u && (O & 0xFFFFu) == 0u) m = 0;
    else if ((O >> 16) == 0x3FF0u) m = 3;
    else if (O <= 1u) m = (so[0] == 0u && se[0] != 0u) ? 3 : 0;
    else if ((O & 0xFEFEFEFEu) == 0u) m = 2;
    mode[0] = m;
  }
}

// ---------------- CSR build: one block per graph ----------------
__global__ __launch_bounds__(256) void k_csr(const int* __restrict__ edges, int estride,
                                             int E, int nodes,
                                             int* __restrict__ rowptr, int rstride,
                                             int* __restrict__ col, int cstride) {
  int g = blockIdx.x, tid = threadIdx.x;
  __shared__ int cnt[1025];
  __shared__ int psum[257];
  const int* src = edges + (size_t)g * estride;
  const int* dst = src + E;
  for (int i = tid; i <= nodes; i += 256) cnt[i] = 0;
  __syncthreads();
  for (int e = tid; e < E; e += 256) atomicAdd(&cnt[dst[e]], 1);
  __syncthreads();
  int base = tid * 4;
  int loc = 0;
#pragma unroll
  for (int i = 0; i < 4; ++i) { int idx = base + i; if (idx < nodes) loc += cnt[idx]; }
  psum[tid + 1] = loc;
  if (tid == 0) psum[0] = 0;
  __syncthreads();
  if (tid == 0) { for (int i = 1; i <= 256; ++i) psum[i] += psum[i - 1]; }
  __syncthreads();
  int run = psum[tid];
  int starts[4];
#pragma unroll
  for (int i = 0; i < 4; ++i) {
    int idx = base + i;
    if (idx < nodes) { int c = cnt[idx]; starts[i] = run; run += c; }
  }
  __syncthreads();
#pragma unroll
  for (int i = 0; i < 4; ++i) {
    int idx = base + i;
    if (idx < nodes) { cnt[idx] = starts[i]; rowptr[(size_t)g * rstride + idx] = starts[i]; }
  }
  if (tid == 0) rowptr[(size_t)g * rstride + nodes] = E;
  __syncthreads();
  for (int e = tid; e < E; e += 256) {
    int pos = atomicAdd(&cnt[dst[e]], 1);
    col[(size_t)g * cstride + pos] = src[e];
  }
}

// ---------------- c partial: grid (NB, 4), 1024 thr ----------------
__global__ __launch_bounds__(1024) void k_c_part(const float* __restrict__ t2,
                                                 const float* __restrict__ score,
                                                 float* __restrict__ cpart) {
  int n = blockIdx.x, part = blockIdx.y;
  int lane = threadIdx.x & 63, ty = threadIdx.x >> 6;
  __shared__ float red[16][304];
  float acc[5] = {0.f, 0.f, 0.f, 0.f, 0.f};
  int l0 = part * 256;
  for (int l = l0 + ty; l < l0 + 256; l += 16) {
    const float* tp = t2 + ((size_t)n * LL + l) * D_;
    const float* sp = score + ((size_t)n * LL + l) * D_;
#pragma unroll
    for (int j = 0; j < 5; ++j) { int d = lane + 64 * j; if (d < D_) acc[j] += tp[d] * sp[d]; }
  }
#pragma unroll
  for (int j = 0; j < 5; ++j) { int d = lane + 64 * j; if (d < D_) red[ty][d] = acc[j]; }
  __syncthreads();
  for (int d = threadIdx.x; d < D_; d += 1024) {
    float s = 0.f;
#pragma unroll
    for (int t = 0; t < 16; ++t) s += red[t][d];
    cpart[((size_t)part * NB + n) * D_ + d] = s;
  }
}

__global__ void k_c_red(const float* __restrict__ cpart, float* __restrict__ c) {
  int idx = blockIdx.x * 256 + threadIdx.x;
  if (idx >= NB * D_) return;
  const int S = NB * D_;
  c[idx] = cpart[idx] + cpart[S + idx] + cpart[2 * S + idx] + cpart[3 * S + idx];
}

__device__ __forceinline__ float clamp_logit(float v) {
  if (!(v > -1e30f)) v = -1e30f;
  if (v > 1e30f) v = 1e30f;
  return v;
}

// ---------------- pa_token logits (wave per row) ----------------
__global__ void k_logits_tok(const float* __restrict__ x, const float* __restrict__ w,
                             const float* __restrict__ b, const void* __restrict__ mask,
                             const int* __restrict__ mmode,
                             float* __restrict__ logits, int rows) {
  int row = blockIdx.x * blockDim.y + threadIdx.y;
  if (row >= rows) return;
  int lane = threadIdx.x;
  const float* xp = x + (size_t)row * D_;
  float acc = 0.f;
  for (int d = lane; d < D_; d += 64) acc += xp[d] * w[d];
#pragma unroll
  for (int off = 32; off; off >>= 1) acc += __shfl_down(acc, off);
  if (lane == 0) {
    float v = clamp_logit(acc + b[0]);
    if (read_mask(mask, row, mmode[0])) v = -INFINITY;
    logits[row] = v;
  }
}

// pa_np logits over (N, L+1): rows l<L from X (bf16, pair loads), row L from c (f32)
__global__ void k_logits_np(const bf16* __restrict__ X, const float* __restrict__ c,
                            const float* __restrict__ w, const float* __restrict__ b,
                            const void* __restrict__ mask, const int* __restrict__ mmode,
                            float* __restrict__ logits) {
  int row = blockIdx.x * blockDim.y + threadIdx.y;
  if (row >= NB * (LL + 1)) return;
  int n = row / (LL + 1), l = row % (LL + 1);
  int lane = threadIdx.x;
  float acc = 0.f;
  if (l < LL) {
    const char* xp = (const char*)(X + ((size_t)n * LL + l) * D_);
#pragma unroll
    for (int t = 0; t < 3; ++t) {
      int d2 = lane + 64 * t;
      if (d2 < 150) {
        unsigned int u = *(const unsigned int*)(xp + d2 * 4);
        float2 wv = *(const float2*)&w[d2 * 2];
        acc += __uint_as_float(u << 16) * wv.x + __uint_as_float(u & 0xFFFF0000u) * wv.y;
      }
    }
  } else {
    const float* cp = c + n * D_;
    for (int d = lane; d < D_; d += 64) acc += cp[d] * w[d];
  }
#pragma unroll
  for (int off = 32; off; off >>= 1) acc += __shfl_down(acc, off);
  if (lane == 0) {
    float v = clamp_logit(acc + b[0]);
    if (read_mask(mask, row, mmode[0])) v = -INFINITY;
    logits[row] = v;
  }
}

// ---------------- softmax weights for u1 (b<64) and u2 (b>=64) ----------------
__global__ __launch_bounds__(1024) void k_pa(const float* __restrict__ lg1,
                                             const float* __restrict__ lg2,
                                             float* __restrict__ pa1,
                                             float* __restrict__ pa2) {
  int b = blockIdx.x, tid = threadIdx.x;
  int which = b >> 6, n = b & 63;
  const float* lg = which ? (lg2 + (size_t)n * (LL + 1)) : (lg1 + (size_t)n * LL);
  float* pa = which ? (pa2 + (size_t)n * (LL + 1)) : (pa1 + (size_t)n * LL);
  __shared__ float red[16];
  __shared__ float stat;
  float v0 = lg[tid];
  float vx = (which && tid == 0) ? lg[LL] : -INFINITY;
  float m = fmaxf(v0, vx);
#pragma unroll
  for (int off = 32; off; off >>= 1) m = fmaxf(m, __shfl_xor(m, off));
  if ((tid & 63) == 0) red[tid >> 6] = m;
  __syncthreads();
  if (tid == 0) {
    float mm = red[0];
    for (int i = 1; i < 16; ++i) mm = fmaxf(mm, red[i]);
    stat = mm;
  }
  __syncthreads();
  float M = stat;
  if (!(M > -INFINITY && M < INFINITY)) M = 0.f;
  float p0 = __expf(v0 - M);
  float px = (which && tid == 0) ? __expf(vx - M) : 0.f;
  float s = p0 + px;
#pragma unroll
  for (int off = 32; off; off >>= 1) s += __shfl_xor(s, off);
  __syncthreads();
  if ((tid & 63) == 0) red[tid >> 6] = s;
  __syncthreads();
  if (tid == 0) {
    float ss = 0.f;
    for (int i = 0; i < 16; ++i) ss += red[i];
    stat = ss;
  }
  __syncthreads();
  float inv = (stat > 0.f) ? 1.f / stat : 0.f;
  pa[tid] = p0 * inv;
  if (which && tid == 0) pa[LL] = px * inv;
}

// ---------------- u1 partial: grid (NB, 4), 1024 thr ----------------
__global__ __launch_bounds__(1024) void k_u1part(const float* __restrict__ pa1,
                                                 const float* __restrict__ t2,
                                                 float* __restrict__ up) {
  int n = blockIdx.x, part = blockIdx.y;
  int lane = threadIdx.x & 63, ty = threadIdx.x >> 6;
  __shared__ float red[16][304];
  float acc[5] = {0.f, 0.f, 0.f, 0.f, 0.f};
  const float* pw = pa1 + (size_t)n * LL;
  int l0 = part * 256;
  for (int l = l0 + ty; l < l0 + 256; l += 16) {
    float w = pw[l];
    const float* tp = t2 + ((size_t)n * LL + l) * D_;
#pragma unroll
    for (int j = 0; j < 5; ++j) { int d = lane + 64 * j; if (d < D_) acc[j] += w * tp[d]; }
  }
#pragma unroll
  for (int j = 0; j < 5; ++j) { int d = lane + 64 * j; if (d < D_) red[ty][d] = acc[j]; }
  __syncthreads();
  for (int d = threadIdx.x; d < D_; d += 1024) {
    float s = 0.f;
#pragma unroll
    for (int t = 0; t < 16; ++t) s += red[t][d];
    up[((size_t)part * NB + n) * D_ + d] = s;
  }
}

// ---------------- u2 partial (X bf16 + c row at part 3) ----------------
__global__ __launch_bounds__(1024) void k_u2part(const float* __restrict__ pa2,
                                                 const bf16* __restrict__ X,
                                                 const float* __restrict__ c,
                                                 float* __restrict__ up) {
  int n = blockIdx.x, part = blockIdx.y;
  int lane = threadIdx.x & 63, ty = threadIdx.x >> 6;
  __shared__ float red[16][304];
  float acc[3][2] = {};
  const float* pw = pa2 + (size_t)n * (LL + 1);
  int l0 = part * 256;
  for (int l = l0 + ty; l < l0 + 256; l += 16) {
    float w = pw[l];
    const char* xp = (const char*)(X + ((size_t)n * LL + l) * D_);
#pragma unroll
    for (int t = 0; t < 3; ++t) {
      int d2 = lane + 64 * t;
      if (d2 < 150) {
        unsigned int u = *(const unsigned int*)(xp + d2 * 4);
        acc[t][0] += w * __uint_as_float(u << 16);
        acc[t][1] += w * __uint_as_float(u & 0xFFFF0000u);
      }
    }
  }
#pragma unroll
  for (int t = 0; t < 3; ++t) {
    int d2 = lane + 64 * t;
    if (d2 < 150) { red[ty][d2 * 2] = acc[t][0]; red[ty][d2 * 2 + 1] = acc[t][1]; }
  }
  __syncthreads();
  for (int d = threadIdx.x; d < D_; d += 1024) {
    float s = 0.f;
#pragma unroll
    for (int t = 0; t < 16; ++t) s += red[t][d];
    if (part == 3) s += pw[LL] * c[(size_t)n * D_ + d];
    up[((size_t)part * NB + n) * D_ + d] = s;
  }
}

__global__ void k_ured(const float* __restrict__ up1, const float* __restrict__ up2,
                       float* __restrict__ u1, float* __restrict__ u2) {
  int idx = blockIdx.x * 256 + threadIdx.x;
  if (idx >= NB * D_) return;
  const int S = NB * D_;
  u1[idx] = up1[idx] + up1[S + idx] + up1[2 * S + idx] + up1[3 * S + idx];
  u2[idx] = up2[idx] + up2[S + idx] + up2[2 * S + idx] + up2[3 * S + idx];
}

// ---------------- wsrc[h,d] = sum_e W[d,h,e]*att_src[h,e] (and wdst) ----------------
__global__ void k_wvec(const float* __restrict__ W, const float* __restrict__ att_src,
                       const float* __restrict__ att_dst, float* __restrict__ wsrc,
                       float* __restrict__ wdst) {
  int idx = blockIdx.x * blockDim.x + threadIdx.x;
  if (idx >= 2 * H_ * D_) return;
  int s = idx / (H_ * D_);
  int r = idx % (H_ * D_);
  int h = r / D_, d = r % D_;
  const float* att = (s ? att_dst : att_src) + h * D_;
  const float* Wp = W + (size_t)d * H_ * D_ + h * D_;
  float acc = 0.f;
  for (int e = 0; e < D_; ++e) acc += Wp[e] * att[e];
  (s ? wdst : wsrc)[h * D_ + d] = acc;
}

// ---------------- a_src/a_dst[row,h] = x[row,:] . wvec[h,:] (pair-vectorized) ----------------
template <typename T>
__global__ void k_asrc(const T* __restrict__ x, const float* __restrict__ wsrc,
                       const float* __restrict__ wdst, float* __restrict__ a_src,
                       float* __restrict__ a_dst, int rows) {
  int row = blockIdx.x * blockDim.y + threadIdx.y;
  if (row >= rows) return;
  int lane = threadIdx.x;
  float xr[3][2];
#pragma unroll
  for (int t = 0; t < 3; ++t) {
    int d2 = lane + 64 * t;
    if (d2 < 150) {
      if constexpr (sizeof(T) == 4) {
        float2 v = *(const float2*)((const float*)x + (size_t)row * D_ + d2 * 2);
        xr[t][0] = v.x; xr[t][1] = v.y;
      } else {
        unsigned int u = *(const unsigned int*)((const char*)x + ((size_t)row * D_) * 2 + d2 * 4);
        xr[t][0] = __uint_as_float(u << 16); xr[t][1] = __uint_as_float(u & 0xFFFF0000u);
      }
    } else { xr[t][0] = 0.f; xr[t][1] = 0.f; }
  }
#pragma unroll
  for (int hh = 0; hh < H_; ++hh) {
    float as = 0.f, ad = 0.f;
#pragma unroll
    for (int t = 0; t < 3; ++t) {
      int d2 = lane + 64 * t;
      if (d2 < 150) {
        float2 ws = *(const float2*)&wsrc[hh * D_ + d2 * 2];
        float2 wd = *(const float2*)&wdst[hh * D_ + d2 * 2];
        as += xr[t][0] * ws.x + xr[t][1] * ws.y;
        ad += xr[t][0] * wd.x + xr[t][1] * wd.y;
      }
    }
#pragma unroll
    for (int off = 32; off; off >>= 1) { as += __shfl_down(as, off); ad += __shfl_down(ad, off); }
    if (lane == 0) { a_src[(size_t)row * H_ + hh] = as; a_dst[(size_t)row * H_ + hh] = ad; }
  }
}

// ---------------- pack Wc: Wcp[d][h*300+e] = W[e,h,d]/H, bf16, (BN2 x KC) ----------------
__global__ void k_packWc(const float* __restrict__ W, bf16* __restrict__ Wcp) {
  int idx = blockIdx.x * 256 + threadIdx.x;
  if (idx >= BN2 * KC) return;
  int j = idx / KC, k = idx - j * KC;
  float v = 0.f;
  if (j < D_ && k < H_ * D_) {
    int h = k / D_, e = k - h * D_;
    v = W[(size_t)e * (H_ * D_) + h * D_ + j] * (1.f / H_);
  }
  Wcp[idx] = f2bf(v);
}

// ---------------- alpha: per-edge softmax weights, wave per node ----------------
// alpha[h*aplane + g*astride + pos] = softmax weight of edge at CSR position pos, head h.
__global__ __launch_bounds__(256) void k_alpha(
    const float* __restrict__ a_src, const float* __restrict__ a_dst,
    const int* __restrict__ rowptr, int rstride,
    const int* __restrict__ col, int cstride,
    int nodes, int lbpg,
    float* __restrict__ alpha, int astride, int aplane) {
  int b = blockIdx.x;
  int wv = threadIdx.x >> 6, lane = threadIdx.x & 63;
  int g = b >> lbpg, nb = b & ((1 << lbpg) - 1);
  int node = (nb << 2) + wv;
  const int* rp = rowptr + (size_t)g * rstride;
  int r0 = rp[node];
  int deg = rp[node + 1] - r0;
  if (deg > MAXDEG) deg = MAXDEG;
  if (deg == 0) return;
  const int* cp = col + (size_t)g * cstride + r0;
  int row0 = g * nodes;
  const float* adr = a_dst + (size_t)(row0 + node) * H_;
  float ad[H_];
#pragma unroll
  for (int hh = 0; hh < H_; ++hh) ad[hh] = adr[hh];
  int d0 = deg < 64 ? deg : 64;
  float l0[H_];
  if (lane < d0) {
    int s0 = cp[lane];
    const float* ap = a_src + (size_t)(row0 + s0) * H_;
#pragma unroll
    for (int hh = 0; hh < H_; ++hh) { float v = ap[hh] + ad[hh]; l0[hh] = v > 0.f ? v : 0.2f * v; }
  } else {
#pragma unroll
    for (int hh = 0; hh < H_; ++hh) l0[hh] = -INFINITY;
  }
  bool two = deg > 64;
  float l1[H_];
#pragma unroll
  for (int hh = 0; hh < H_; ++hh) l1[hh] = -INFINITY;
  if (two && lane < deg - 64) {
    int s1 = cp[64 + lane];
    const float* ap = a_src + (size_t)(row0 + s1) * H_;
#pragma unroll
    for (int hh = 0; hh < H_; ++hh) { float v = ap[hh] + ad[hh]; l1[hh] = v > 0.f ? v : 0.2f * v; }
  }
  float* alg = alpha + (size_t)g * astride + r0;
#pragma unroll
  for (int hh = 0; hh < H_; ++hh) {
    float m = two ? fmaxf(l0[hh], l1[hh]) : l0[hh];
    for (int off = 1; off < deg && off < 64; off <<= 1) m = fmaxf(m, __shfl_xor(m, off));
    m = __shfl(m, 0);
    float e0 = (lane < d0) ? __expf(l0[hh] - m) : 0.f;
    float e1 = (two && lane < deg - 64) ? __expf(l1[hh] - m) : 0.f;
    float s = e0 + e1;
    for (int off = 1; off < deg && off < 64; off <<= 1) s += __shfl_xor(s, off);
    s = __shfl(s, 0);
    float inv = 1.f / (s + 1e-16f);
    if (lane < d0) alg[(size_t)hh * aplane + lane] = e0 * inv;
    if (two && lane < deg - 64) alg[(size_t)hh * aplane + 64 + lane] = e1 * inv;
  }
}

// ---------------- fused gather-GEMM: builds A-tile from x via CSR+alpha per K-step ----
// Block: 64 rows x 320 cols, 4 waves (wave = 64 rows x 80 cols), K-loop 47 steps.
// A-tile Zs[64][32] built in LDS from x rows (L2-resident); B reg-prefetched 1 step ahead.
// Epilogue: fused bias+mask+relu+LayerNorm (identical to verified round-3 code).
union SmemU {
  struct { short As[BM2][40]; short Bs[BN2][40]; } s;
  unsigned short Osh[64][304];
};

template <typename T>
__global__ __launch_bounds__(256) void k_gemm2f(
    const T* __restrict__ x, const bf16* __restrict__ Wcp,
    const int* __restrict__ rowptr, int rstride,
    const int* __restrict__ col, int cstride,
    const float* __restrict__ alpha, int astride, int aplane,
    int nodes,
    const float* __restrict__ bias,
    const void* __restrict__ gmask, const int* __restrict__ mmode,
    const float* __restrict__ g_ln, const float* __restrict__ b_ln,
    bf16* __restrict__ xout) {
  __shared__ SmemU u;
  __shared__ float sS[4][64], sQ[4][64];
  __shared__ float sMu[64], sRs[64];
  int tid = threadIdx.x;
  int wave = tid >> 6, lane = tid & 63;
  int cl = lane & 15, qw = lane >> 4;
  int brow = blockIdx.x * BM2;
  int g = brow / nodes;
  int nl0 = brow - g * nodes;
  // build job: this thread owns row brj, cols [bq*8, bq*8+8) of each K-slice
  int brj = tid >> 2, bq = tid & 3;
  const int* rp = rowptr + (size_t)g * rstride;
  int r0 = rp[nl0 + brj];
  int deg = rp[nl0 + brj + 1] - r0;
  if (deg > MAXDEG) deg = MAXDEG;
  const int* cp = col + (size_t)g * cstride;
  const float* alg = alpha + (size_t)g * astride;
  const T* xg = x + (size_t)g * nodes * D_;
  // B prefetch (5 x uint4 per thread covers 320x32 slice)
  const uint4* wp = (const uint4*)Wcp;
  int brr[5], bch[5];
#pragma unroll
  for (int k = 0; k < 5; ++k) { int cjob = tid + k * 256; brr[k] = cjob >> 2; bch[k] = cjob & 3; }
  uint4 breg[5];
#pragma unroll
  for (int k = 0; k < 5; ++k) breg[k] = wp[(size_t)brr[k] * (KC / 8) + bch[k]];

  f32x4 acc[4][5] = {};
  for (int ks = 0; ks < 47; ++ks) {
    int k0 = ks * 32;
    // ---- build A-tile slice: Zs[brj][bq*8 .. +8] ----
    {
      float a8[8] = {0.f,0.f,0.f,0.f,0.f,0.f,0.f,0.f};
      int kbase = k0 + bq * 8;
      if (kbase < 1500) {
        int h0 = (kbase >= 300) + (kbase >= 600) + (kbase >= 900) + (kbase >= 1200);
        int hb = (h0 + 1) * 300;  // boundary where head increments
        for (int i = 0; i < deg; ++i) {
          int s = cp[r0 + i];
          const T* xr = xg + (size_t)s * D_;
          float a0 = alg[(size_t)h0 * aplane + r0 + i];
          float a1 = (kbase + 7 >= hb && h0 < 4) ? alg[(size_t)(h0 + 1) * aplane + r0 + i] : a0;
#pragma unroll
          for (int c2 = 0; c2 < 8; ++c2) {
            int kc = kbase + c2;
            if (kc < 1500) {
              int up = (kc >= hb) ? 1 : 0;
              float aa = up ? a1 : a0;
              int ec = kc - h0 * 300 - up * 300;
              a8[c2] += aa * toF(xr[ec]);
            }
          }
        }
      }
      short8 zs;
#pragma unroll
      for (int c2 = 0; c2 < 8; ++c2) { bf16 bv = f2bf(a8[c2]); zs[c2] = *(short*)&bv; }
      *(short8*)&u.s.As[brj][bq * 8] = zs;
    }
    // ---- write B slice from prefetch regs ----
#pragma unroll
    for (int k = 0; k < 5; ++k)
      *(uint4*)&u.s.Bs[brr[k]][bch[k] << 3] = breg[k];
    __syncthreads();
    // ---- issue next B loads (latency hides under MFMA) ----
    if (ks + 1 < 47) {
      int kn = (k0 + 32) >> 3;
#pragma unroll
      for (int k = 0; k < 5; ++k)
        breg[k] = wp[(size_t)brr[k] * (KC / 8) + kn + bch[k]];
    }
    int kq = qw << 3;
    short8 af[4];
#pragma unroll
    for (int i = 0; i < 4; ++i) af[i] = *(const short8*)&u.s.As[i * 16 + cl][kq];
#pragma unroll
    for (int j = 0; j < 5; ++j) {
      short8 bfr = *(const short8*)&u.s.Bs[wave * 80 + j * 16 + cl][kq];
#pragma unroll
      for (int i = 0; i < 4; ++i)
        acc[i][j] = __builtin_amdgcn_mfma_f32_16x16x32_bf16(af[i], bfr, acc[i][j], 0, 0, 0);
    }
    __syncthreads();
  }
  // ---- epilogue: bias + mask + relu, row stats, LN, store ----
  int msk = gmask ? read_mask(gmask, g, mmode[0]) : 0;
  float rs[4][4], rq[4][4];
#pragma unroll
  for (int i = 0; i < 4; ++i)
#pragma unroll
    for (int r = 0; r < 4; ++r) { rs[i][r] = 0.f; rq[i][r] = 0.f; }
#pragma unroll
  for (int i = 0; i < 4; ++i)
#pragma unroll
    for (int j = 0; j < 5; ++j) {
      int colc = wave * 80 + j * 16 + cl;
      bool cv = colc < D_;
      float bb = cv ? bias[colc] : 0.f;
#pragma unroll
      for (int r = 0; r < 4; ++r) {
        float y = acc[i][j][r] + bb;
        if (msk) y = 0.f;
        y = fmaxf(y, 0.f);
        if (!cv) y = 0.f;
        acc[i][j][r] = y;
        rs[i][r] += y;
        rq[i][r] += y * y;
      }
    }
#pragma unroll
  for (int off = 1; off < 16; off <<= 1) {
#pragma unroll
    for (int i = 0; i < 4; ++i)
#pragma unroll
      for (int r = 0; r < 4; ++r) {
        rs[i][r] += __shfl_xor(rs[i][r], off);
        rq[i][r] += __shfl_xor(rq[i][r], off);
      }
  }
  if (cl == 0) {
#pragma unroll
    for (int i = 0; i < 4; ++i)
#pragma unroll
      for (int r = 0; r < 4; ++r) {
        sS[wave][i * 16 + qw * 4 + r] = rs[i][r];
        sQ[wave][i * 16 + qw * 4 + r] = rq[i][r];
      }
  }
  __syncthreads();
  if (tid < 64) {
    float s = sS[0][tid] + sS[1][tid] + sS[2][tid] + sS[3][tid];
    float q = sQ[0][tid] + sQ[1][tid] + sQ[2][tid] + sQ[3][tid];
    float mu = s * (1.f / 300.f);
    float var = q * (1.f / 300.f) - mu * mu;
    var = fmaxf(var, 0.f);
    sMu[tid] = mu;
    sRs[tid] = rsqrtf(var + 1e-5f);
  }
  __syncthreads();
#pragma unroll
  for (int i = 0; i < 4; ++i)
#pragma unroll
    for (int j = 0; j < 5; ++j) {
      int colc = wave * 80 + j * 16 + cl;
      if (colc < D_) {
        float gv = g_ln[colc], bv = b_ln[colc];
#pragma unroll
        for (int r = 0; r < 4; ++r) {
          int row = i * 16 + qw * 4 + r;
          float o = (acc[i][j][r] - sMu[row]) * sRs[row] * gv + bv;
          bf16 cb = f2bf(o);
          u.Osh[row][colc] = *(unsigned short*)&cb;
        }
      }
    }
  __syncthreads();
  char* ob = (char*)(xout + (size_t)brow * D_);
  for (int idx = tid; idx < 64 * 150; idx += 256) {
    int r = idx / 150, c2 = idx - r * 150;
    *(unsigned int*)(ob + (size_t)r * 600 + c2 * 4) = *(const unsigned int*)&u.Osh[r][c2 * 2];
  }
}

// ---------------- final: out[n, k]=a1, out[n, K+k]=a2 (f32 out) ----------------
__global__ void k_out(const float* __restrict__ u1, const float* __restrict__ u2,
                      const float* __restrict__ v2, const bf16* __restrict__ v3,
                      float* __restrict__ out) {
  int idx = blockIdx.x * blockDim.y + threadIdx.y;
  if (idx >= NB * KK) return;
  int n = idx / KK, k = idx - n * KK;
  int lane = threadIdx.x;
  const float* ap = v2 + (size_t)idx * D_;
  const bf16* bp = v3 + (size_t)idx * D_;
  const float* u1p = u1 + n * D_;
  const float* u2p = u2 + n * D_;
  float a1 = 0.f, a2 = 0.f;
  for (int d = lane; d < D_; d += 64) { a1 += u1p[d] * ap[d]; a2 += u2p[d] * toF(bp[d]); }
#pragma unroll
  for (int off = 32; off; off >>= 1) { a1 += __shfl_down(a1, off); a2 += __shfl_down(a2, off); }
  if (lane == 0) {
    const float scale = 0.05773502691896258f;  // 1/sqrt(300)
    out[(size_t)n * 2 * KK + k] = a1 * scale;
    out[(size_t)n * 2 * KK + KK + k] = a2 * scale;
  }
}

extern "C" void kernel_launch(void* const* d_in, const int* in_sizes, int n_in,
                              void* d_out, int out_size, void* d_ws, size_t ws_size,
                              hipStream_t stream) {
  const float* t2    = (const float*)d_in[0];
  const float* v2    = (const float*)d_in[1];
  const float* score = (const float*)d_in[2];
  const int*   eidx  = (const int*)d_in[3];
  const void*  gmask = d_in[4];
  const void*  kpm   = d_in[5];
  const void*  npm   = d_in[6];
  const int*   iedge = (const int*)d_in[7];
  const float* txtW  = (const float*)d_in[8];
  const float* txtAs = (const float*)d_in[9];
  const float* txtAd = (const float*)d_in[10];
  const float* txtB  = (const float*)d_in[11];
  const float* imgW  = (const float*)d_in[12];
  const float* imgAs = (const float*)d_in[13];
  const float* imgAd = (const float*)d_in[14];
  const float* imgB  = (const float*)d_in[15];
  const float* w1    = (const float*)d_in[16];
  const float* b1    = (const float*)d_in[17];
  const float* w2    = (const float*)d_in[18];
  const float* b2    = (const float*)d_in[19];
  const float* lng   = (const float*)d_in[20];
  const float* lnb   = (const float*)d_in[21];
  float* out = (float*)d_out;

  char* ws = (char*)d_ws;
  size_t off = 0;
  auto alloc = [&](size_t bytes) -> char* {
    char* p = ws + off;
    off += (bytes + 511) & ~(size_t)511;
    return p;
  };
  int*   mmode  = (int*)alloc(64);
  float* c      = (float*)alloc((size_t)NB * D_ * 4);
  float* u1     = (float*)alloc((size_t)NB * D_ * 4);
  float* u2     = (float*)alloc((size_t)NB * D_ * 4);
  float* lg1    = (float*)alloc((size_t)NB * LL * 4);
  float* lg2    = (float*)alloc((size_t)NB * (LL + 1) * 4);
  float* pa1    = (float*)alloc((size_t)NB * LL * 4);
  float* pa2    = (float*)alloc((size_t)NB * (LL + 1) * 4);
  float* cpart  = (float*)alloc((size_t)4 * NB * D_ * 4);
  float* up1    = (float*)alloc((size_t)4 * NB * D_ * 4);
  float* up2    = (float*)alloc((size_t)4 * NB * D_ * 4);
  float* wsrc   = (float*)alloc((size_t)H_ * D_ * 4);
  float* wdst   = (float*)alloc((size_t)H_ * D_ * 4);
  float* asrc   = (float*)alloc((size_t)NB * LL * H_ * 4);
  float* adst   = (float*)alloc((size_t)NB * LL * H_ * 4);
  int*   trp    = (int*)alloc((size_t)NB * (LL + 1) * 4);
  int*   tcol   = (int*)alloc((size_t)NB * ETXT * 4);
  int*   irp    = (int*)alloc((size_t)(KK + 1) * 4);
  int*   icol   = (int*)alloc((size_t)EIMG * 4);
  float* alphaT = (float*)alloc((size_t)H_ * NB * ETXT * 4);
  float* alphaI = (float*)alloc((size_t)H_ * NB * EIMG * 4);
  bf16*  XA     = (bf16*)alloc((size_t)NB * LL * D_ * 2);
  bf16*  XB     = (bf16*)alloc((size_t)NB * LL * D_ * 2);
  bf16*  VA     = (bf16*)alloc((size_t)NB * KK * D_ * 2);
  bf16*  VB     = (bf16*)alloc((size_t)NB * KK * D_ * 2);
  bf16*  Wcp    = (bf16*)alloc((size_t)BN2 * KC * 2);

  dim3 b64x4(64, 4);

  k_detect<<<1, 256, 0, stream>>>((const unsigned int*)kpm, NB * LL / 4, mmode);

  // CSR build (edges identical across layers -> build once)
  k_csr<<<NB, 256, 0, stream>>>(eidx, 2 * ETXT, ETXT, LL, trp, LL + 1, tcol, ETXT);
  k_csr<<<1, 256, 0, stream>>>(iedge, 0, EIMG, KK, irp, 0, icol, 0);

  // phase 0: c, pa_token logits
  k_c_part<<<dim3(NB, 4), 1024, 0, stream>>>(t2, score, cpart);
  k_c_red<<<(NB * D_ + 255) / 256, 256, 0, stream>>>(cpart, c);
  k_logits_tok<<<(NB * LL + 3) / 4, b64x4, 0, stream>>>(t2, w1, b1, kpm, mmode, lg1, NB * LL);

  const int APLT = NB * ETXT;
  const int APLI = NB * EIMG;

  // text GAT (2 layers), fused gather-GEMM, double-buffered state
  for (int layer = 0; layer < 2; ++layer) {
    const float* W = txtW + (size_t)layer * D_ * H_ * D_;
    k_packWc<<<(BN2 * KC + 255) / 256, 256, 0, stream>>>(W, Wcp);
    k_wvec<<<(2 * H_ * D_ + 255) / 256, 256, 0, stream>>>(
        W, txtAs + layer * H_ * D_, txtAd + layer * H_ * D_, wsrc, wdst);
    if (layer == 0) {
      k_asrc<float><<<(NB * LL + 3) / 4, b64x4, 0, stream>>>(t2, wsrc, wdst, asrc, adst, NB * LL);
      k_alpha<<<NB * (LL / 4), 256, 0, stream>>>(asrc, adst, trp, LL + 1, tcol, ETXT,
                                                 LL, 8, alphaT, ETXT, APLT);
      k_gemm2f<float><<<NB * LL / BM2, 256, 0, stream>>>(
          t2, Wcp, trp, LL + 1, tcol, ETXT, alphaT, ETXT, APLT, LL,
          txtB + layer * D_, gmask, mmode, lng, lnb, XA);
    } else {
      k_asrc<bf16><<<(NB * LL + 3) / 4, b64x4, 0, stream>>>(XA, wsrc, wdst, asrc, adst, NB * LL);
      k_alpha<<<NB * (LL / 4), 256, 0, stream>>>(asrc, adst, trp, LL + 1, tcol, ETXT,
                                                 LL, 8, alphaT, ETXT, APLT);
      k_gemm2f<bf16><<<NB * LL / BM2, 256, 0, stream>>>(
          XA, Wcp, trp, LL + 1, tcol, ETXT, alphaT, ETXT, APLT, LL,
          txtB + layer * D_, gmask, mmode, lng, lnb, XB);
    }
  }

  // image GAT (2 layers), shared edges, no gnn_mask
  for (int layer = 0; layer < 2; ++layer) {
    const float* W = imgW + (size_t)layer * D_ * H_ * D_;
    k_packWc<<<(BN2 * KC + 255) / 256, 256, 0, stream>>>(W, Wcp);
    k_wvec<<<(2 * H_ * D_ + 255) / 256, 256, 0, stream>>>(
        W, imgAs + layer * H_ * D_, imgAd + layer * H_ * D_, wsrc, wdst);
    if (layer == 0) {
      k_asrc<float><<<(NB * KK + 3) / 4, b64x4, 0, stream>>>(v2, wsrc, wdst, asrc, adst, NB * KK);
      k_alpha<<<NB * (KK / 4), 256, 0, stream>>>(asrc, adst, irp, 0, icol, 0,
                                                 KK, 4, alphaI, EIMG, APLI);
      k_gemm2f<float><<<NB * KK / BM2, 256, 0, stream>>>(
          v2, Wcp, irp, 0, icol, 0, alphaI, EIMG, APLI, KK,
          imgB + layer * D_, nullptr, mmode, lng, lnb, VA);
    } else {
      k_asrc<bf16><<<(NB * KK + 3) / 4, b64x4, 0, stream>>>(VA, wsrc, wdst, asrc, adst, NB * KK);
      k_alpha<<<NB * (KK / 4), 256, 0, stream>>>(asrc, adst, irp, 0, icol, 0,
                                                 KK, 4, alphaI, EIMG, APLI);
      k_gemm2f<bf16><<<NB * KK / BM2, 256, 0, stream>>>(
          VA, Wcp, irp, 0, icol, 0, alphaI, EIMG, APLI, KK,
          imgB + layer * D_, nullptr, mmode, lng, lnb, VB);
    }
  }

  // epilogue: pa_np logits, both softmaxes, weighted sums, output
  k_logits_np<<<(NB * (LL + 1) + 3) / 4, b64x4, 0, stream>>>(XB, c, w2, b2, npm, mmode, lg2);
  k_pa<<<128, 1024, 0, stream>>>(lg1, lg2, pa1, pa2);
  k_u1part<<<dim3(NB, 4), 1024, 0, stream>>>(pa1, t2, up1);
  k_u2part<<<dim3(NB, 4), 1024, 0, stream>>>(pa2, XB, c, up2);
  k_ured<<<(NB * D_ + 255) / 256, 256, 0, stream>>>(up1, up2, u1, u2);
  k_out<<<(NB * KK + 3) / 4, b64x4, 0, stream>>>(u1, u2, v2, VB, out);
}

// Round 5
// 1078.756 us; speedup vs baseline: 3.3977x; 3.3977x over previous
//
#include <hip/hip_runtime.h>
#include <hip/hip_bf16.h>
#include <math.h>

typedef __hip_bfloat16 bf16;
__device__ __forceinline__ float toF(float v){ return v; }
__device__ __forceinline__ float toF(bf16 v){ return __bfloat162float(v); }
__device__ __forceinline__ bf16 f2bf(float v){ return __float2bfloat16(v); }

#define D_    300
#define H_    5
#define NB    64
#define LL    1024
#define KK    64
#define ETXT  2048
#define EIMG  512
#define MAXDEG 128
#define KP    320    // K padded (300 -> 320)
#define NP    1536   // N padded (1500 -> 1536, 12 tiles of 128)

typedef __attribute__((ext_vector_type(8))) short short8;
typedef __attribute__((ext_vector_type(4))) float f32x4;

// Mask storage modes: 0 = 4-byte word (int32/f32), 1 = 2-byte, 2 = 1-byte (bool), 3 = 8-byte.
__device__ __forceinline__ int read_mask(const void* p, int i, int mode) {
  switch (mode) {
    case 1: return ((const unsigned short*)p)[i] != 0;
    case 2: return ((const unsigned char*)p)[i] != 0;
    case 3: { const unsigned int* w = (const unsigned int*)p;
              return (w[2*i] | w[2*i+1]) != 0; }
    default: return ((const unsigned int*)p)[i] != 0;
  }
}

__global__ void k_detect(const unsigned int* __restrict__ w, int nwords,
                         int* __restrict__ mode) {
  __shared__ unsigned int se[256], so[256];
  unsigned int oe = 0, oo = 0;
  for (int i = threadIdx.x; i < nwords; i += 256) {
    unsigned int v = w[i];
    if (i & 1) oo |= v; else oe |= v;
  }
  se[threadIdx.x] = oe; so[threadIdx.x] = oo;
  __syncthreads();
  for (int s = 128; s; s >>= 1) {
    if (threadIdx.x < s) { se[threadIdx.x] |= se[threadIdx.x+s]; so[threadIdx.x] |= so[threadIdx.x+s]; }
    __syncthreads();
  }
  if (threadIdx.x == 0) {
    unsigned int O = se[0] | so[0];
    int m = 0;
    if (O == 0u) m = 0;
    else if ((O & 0xFFFFu) == 0x3F80u) m = 1;
    else if ((O >> 16) == 0x3F80u && (O & 0xFFFFu) == 0u) m = 0;
    else if ((O >> 16) == 0x3FF0u) m = 3;
    else if (O <= 1u) m = (so[0] == 0u && se[0] != 0u) ? 3 : 0;
    else if ((O & 0xFEFEFEFEu) == 0u) m = 2;
    mode[0] = m;
  }
}

// ---------------- CSR build: one block per graph ----------------
__global__ __launch_bounds__(256) void k_csr(const int* __restrict__ edges, int estride,
                                             int E, int nodes,
                                             int* __restrict__ rowptr, int rstride,
                                             int* __restrict__ col, int cstride) {
  int g = blockIdx.x, tid = threadIdx.x;
  __shared__ int cnt[1025];
  __shared__ int psum[257];
  const int* src = edges + (size_t)g * estride;
  const int* dst = src + E;
  for (int i = tid; i <= nodes; i += 256) cnt[i] = 0;
  __syncthreads();
  for (int e = tid; e < E; e += 256) atomicAdd(&cnt[dst[e]], 1);
  __syncthreads();
  int base = tid * 4;
  int loc = 0;
#pragma unroll
  for (int i = 0; i < 4; ++i) { int idx = base + i; if (idx < nodes) loc += cnt[idx]; }
  psum[tid + 1] = loc;
  if (tid == 0) psum[0] = 0;
  __syncthreads();
  if (tid == 0) { for (int i = 1; i <= 256; ++i) psum[i] += psum[i - 1]; }
  __syncthreads();
  int run = psum[tid];
  int starts[4];
#pragma unroll
  for (int i = 0; i < 4; ++i) {
    int idx = base + i;
    if (idx < nodes) { int c = cnt[idx]; starts[i] = run; run += c; }
  }
  __syncthreads();
#pragma unroll
  for (int i = 0; i < 4; ++i) {
    int idx = base + i;
    if (idx < nodes) { cnt[idx] = starts[i]; rowptr[(size_t)g * rstride + idx] = starts[i]; }
  }
  if (tid == 0) rowptr[(size_t)g * rstride + nodes] = E;
  __syncthreads();
  for (int e = tid; e < E; e += 256) {
    int pos = atomicAdd(&cnt[dst[e]], 1);
    col[(size_t)g * cstride + pos] = src[e];
  }
}

// ---------------- c partial: grid (NB, 4), 1024 thr ----------------
__global__ __launch_bounds__(1024) void k_c_part(const float* __restrict__ t2,
                                                 const float* __restrict__ score,
                                                 float* __restrict__ cpart) {
  int n = blockIdx.x, part = blockIdx.y;
  int lane = threadIdx.x & 63, ty = threadIdx.x >> 6;
  __shared__ float red[16][304];
  float acc[5] = {0.f, 0.f, 0.f, 0.f, 0.f};
  int l0 = part * 256;
  for (int l = l0 + ty; l < l0 + 256; l += 16) {
    const float* tp = t2 + ((size_t)n * LL + l) * D_;
    const float* sp = score + ((size_t)n * LL + l) * D_;
#pragma unroll
    for (int j = 0; j < 5; ++j) { int d = lane + 64 * j; if (d < D_) acc[j] += tp[d] * sp[d]; }
  }
#pragma unroll
  for (int j = 0; j < 5; ++j) { int d = lane + 64 * j; if (d < D_) red[ty][d] = acc[j]; }
  __syncthreads();
  for (int d = threadIdx.x; d < D_; d += 1024) {
    float s = 0.f;
#pragma unroll
    for (int t = 0; t < 16; ++t) s += red[t][d];
    cpart[((size_t)part * NB + n) * D_ + d] = s;
  }
}

__global__ void k_c_red(const float* __restrict__ cpart, float* __restrict__ c) {
  int idx = blockIdx.x * 256 + threadIdx.x;
  if (idx >= NB * D_) return;
  const int S = NB * D_;
  c[idx] = cpart[idx] + cpart[S + idx] + cpart[2 * S + idx] + cpart[3 * S + idx];
}

__device__ __forceinline__ float clamp_logit(float v) {
  if (!(v > -1e30f)) v = -1e30f;
  if (v > 1e30f) v = 1e30f;
  return v;
}

// ---------------- pa_token logits (wave per row) ----------------
__global__ void k_logits_tok(const float* __restrict__ x, const float* __restrict__ w,
                             const float* __restrict__ b, const void* __restrict__ mask,
                             const int* __restrict__ mmode,
                             float* __restrict__ logits, int rows) {
  int row = blockIdx.x * blockDim.y + threadIdx.y;
  if (row >= rows) return;
  int lane = threadIdx.x;
  const float* xp = x + (size_t)row * D_;
  float acc = 0.f;
  for (int d = lane; d < D_; d += 64) acc += xp[d] * w[d];
#pragma unroll
  for (int off = 32; off; off >>= 1) acc += __shfl_down(acc, off);
  if (lane == 0) {
    float v = clamp_logit(acc + b[0]);
    if (read_mask(mask, row, mmode[0])) v = -INFINITY;
    logits[row] = v;
  }
}

// pa_np logits over (N, L+1): rows l<L from X (bf16, pair loads), row L from c (f32)
__global__ void k_logits_np(const bf16* __restrict__ X, const float* __restrict__ c,
                            const float* __restrict__ w, const float* __restrict__ b,
                            const void* __restrict__ mask, const int* __restrict__ mmode,
                            float* __restrict__ logits) {
  int row = blockIdx.x * blockDim.y + threadIdx.y;
  if (row >= NB * (LL + 1)) return;
  int n = row / (LL + 1), l = row % (LL + 1);
  int lane = threadIdx.x;
  float acc = 0.f;
  if (l < LL) {
    const char* xp = (const char*)(X + ((size_t)n * LL + l) * D_);
#pragma unroll
    for (int t = 0; t < 3; ++t) {
      int d2 = lane + 64 * t;
      if (d2 < 150) {
        unsigned int u = *(const unsigned int*)(xp + d2 * 4);
        float2 wv = *(const float2*)&w[d2 * 2];
        acc += __uint_as_float(u << 16) * wv.x + __uint_as_float(u & 0xFFFF0000u) * wv.y;
      }
    }
  } else {
    const float* cp = c + n * D_;
    for (int d = lane; d < D_; d += 64) acc += cp[d] * w[d];
  }
#pragma unroll
  for (int off = 32; off; off >>= 1) acc += __shfl_down(acc, off);
  if (lane == 0) {
    float v = clamp_logit(acc + b[0]);
    if (read_mask(mask, row, mmode[0])) v = -INFINITY;
    logits[row] = v;
  }
}

// ---------------- softmax weights for u1 (b<64) and u2 (b>=64) ----------------
__global__ __launch_bounds__(1024) void k_pa(const float* __restrict__ lg1,
                                             const float* __restrict__ lg2,
                                             float* __restrict__ pa1,
                                             float* __restrict__ pa2) {
  int b = blockIdx.x, tid = threadIdx.x;
  int which = b >> 6, n = b & 63;
  const float* lg = which ? (lg2 + (size_t)n * (LL + 1)) : (lg1 + (size_t)n * LL);
  float* pa = which ? (pa2 + (size_t)n * (LL + 1)) : (pa1 + (size_t)n * LL);
  __shared__ float red[16];
  __shared__ float stat;
  float v0 = lg[tid];
  float vx = (which && tid == 0) ? lg[LL] : -INFINITY;
  float m = fmaxf(v0, vx);
#pragma unroll
  for (int off = 32; off; off >>= 1) m = fmaxf(m, __shfl_xor(m, off));
  if ((tid & 63) == 0) red[tid >> 6] = m;
  __syncthreads();
  if (tid == 0) {
    float mm = red[0];
    for (int i = 1; i < 16; ++i) mm = fmaxf(mm, red[i]);
    stat = mm;
  }
  __syncthreads();
  float M = stat;
  if (!(M > -INFINITY && M < INFINITY)) M = 0.f;
  float p0 = __expf(v0 - M);
  float px = (which && tid == 0) ? __expf(vx - M) : 0.f;
  float s = p0 + px;
#pragma unroll
  for (int off = 32; off; off >>= 1) s += __shfl_xor(s, off);
  __syncthreads();
  if ((tid & 63) == 0) red[tid >> 6] = s;
  __syncthreads();
  if (tid == 0) {
    float ss = 0.f;
    for (int i = 0; i < 16; ++i) ss += red[i];
    stat = ss;
  }
  __syncthreads();
  float inv = (stat > 0.f) ? 1.f / stat : 0.f;
  pa[tid] = p0 * inv;
  if (which && tid == 0) pa[LL] = px * inv;
}

// ---------------- u1 partial: grid (NB, 4), 1024 thr ----------------
__global__ __launch_bounds__(1024) void k_u1part(const float* __restrict__ pa1,
                                                 const float* __restrict__ t2,
                                                 float* __restrict__ up) {
  int n = blockIdx.x, part = blockIdx.y;
  int lane = threadIdx.x & 63, ty = threadIdx.x >> 6;
  __shared__ float red[16][304];
  float acc[5] = {0.f, 0.f, 0.f, 0.f, 0.f};
  const float* pw = pa1 + (size_t)n * LL;
  int l0 = part * 256;
  for (int l = l0 + ty; l < l0 + 256; l += 16) {
    float w = pw[l];
    const float* tp = t2 + ((size_t)n * LL + l) * D_;
#pragma unroll
    for (int j = 0; j < 5; ++j) { int d = lane + 64 * j; if (d < D_) acc[j] += w * tp[d]; }
  }
#pragma unroll
  for (int j = 0; j < 5; ++j) { int d = lane + 64 * j; if (d < D_) red[ty][d] = acc[j]; }
  __syncthreads();
  for (int d = threadIdx.x; d < D_; d += 1024) {
    float s = 0.f;
#pragma unroll
    for (int t = 0; t < 16; ++t) s += red[t][d];
    up[((size_t)part * NB + n) * D_ + d] = s;
  }
}

// ---------------- u2 partial (X bf16 + c row at part 3) ----------------
__global__ __launch_bounds__(1024) void k_u2part(const float* __restrict__ pa2,
                                                 const bf16* __restrict__ X,
                                                 const float* __restrict__ c,
                                                 float* __restrict__ up) {
  int n = blockIdx.x, part = blockIdx.y;
  int lane = threadIdx.x & 63, ty = threadIdx.x >> 6;
  __shared__ float red[16][304];
  float acc[3][2] = {};
  const float* pw = pa2 + (size_t)n * (LL + 1);
  int l0 = part * 256;
  for (int l = l0 + ty; l < l0 + 256; l += 16) {
    float w = pw[l];
    const char* xp = (const char*)(X + ((size_t)n * LL + l) * D_);
#pragma unroll
    for (int t = 0; t < 3; ++t) {
      int d2 = lane + 64 * t;
      if (d2 < 150) {
        unsigned int u = *(const unsigned int*)(xp + d2 * 4);
        acc[t][0] += w * __uint_as_float(u << 16);
        acc[t][1] += w * __uint_as_float(u & 0xFFFF0000u);
      }
    }
  }
#pragma unroll
  for (int t = 0; t < 3; ++t) {
    int d2 = lane + 64 * t;
    if (d2 < 150) { red[ty][d2 * 2] = acc[t][0]; red[ty][d2 * 2 + 1] = acc[t][1]; }
  }
  __syncthreads();
  for (int d = threadIdx.x; d < D_; d += 1024) {
    float s = 0.f;
#pragma unroll
    for (int t = 0; t < 16; ++t) s += red[t][d];
    if (part == 3) s += pw[LL] * c[(size_t)n * D_ + d];
    up[((size_t)part * NB + n) * D_ + d] = s;
  }
}

__global__ void k_ured(const float* __restrict__ up1, const float* __restrict__ up2,
                       float* __restrict__ u1, float* __restrict__ u2) {
  int idx = blockIdx.x * 256 + threadIdx.x;
  if (idx >= NB * D_) return;
  const int S = NB * D_;
  u1[idx] = up1[idx] + up1[S + idx] + up1[2 * S + idx] + up1[3 * S + idx];
  u2[idx] = up2[idx] + up2[S + idx] + up2[2 * S + idx] + up2[3 * S + idx];
}

// ---------------- wsrc[h,d] = sum_e W[d,h,e]*att_src[h,e] (and wdst) ----------------
__global__ void k_wvec(const float* __restrict__ W, const float* __restrict__ att_src,
                       const float* __restrict__ att_dst, float* __restrict__ wsrc,
                       float* __restrict__ wdst) {
  int idx = blockIdx.x * blockDim.x + threadIdx.x;
  if (idx >= 2 * H_ * D_) return;
  int s = idx / (H_ * D_);
  int r = idx % (H_ * D_);
  int h = r / D_, d = r % D_;
  const float* att = (s ? att_dst : att_src) + h * D_;
  const float* Wp = W + (size_t)d * H_ * D_ + h * D_;
  float acc = 0.f;
  for (int e = 0; e < D_; ++e) acc += Wp[e] * att[e];
  (s ? wdst : wsrc)[h * D_ + d] = acc;
}

// ---------------- a_src/a_dst[row,h] = x[row,:] . wvec[h,:] (pair-vectorized) ----------------
template <typename T>
__global__ void k_asrc(const T* __restrict__ x, const float* __restrict__ wsrc,
                       const float* __restrict__ wdst, float* __restrict__ a_src,
                       float* __restrict__ a_dst, int rows) {
  int row = blockIdx.x * blockDim.y + threadIdx.y;
  if (row >= rows) return;
  int lane = threadIdx.x;
  float xr[3][2];
#pragma unroll
  for (int t = 0; t < 3; ++t) {
    int d2 = lane + 64 * t;
    if (d2 < 150) {
      if constexpr (sizeof(T) == 4) {
        float2 v = *(const float2*)((const float*)x + (size_t)row * D_ + d2 * 2);
        xr[t][0] = v.x; xr[t][1] = v.y;
      } else {
        unsigned int u = *(const unsigned int*)((const char*)x + ((size_t)row * D_) * 2 + d2 * 4);
        xr[t][0] = __uint_as_float(u << 16); xr[t][1] = __uint_as_float(u & 0xFFFF0000u);
      }
    } else { xr[t][0] = 0.f; xr[t][1] = 0.f; }
  }
#pragma unroll
  for (int hh = 0; hh < H_; ++hh) {
    float as = 0.f, ad = 0.f;
#pragma unroll
    for (int t = 0; t < 3; ++t) {
      int d2 = lane + 64 * t;
      if (d2 < 150) {
        float2 ws = *(const float2*)&wsrc[hh * D_ + d2 * 2];
        float2 wd = *(const float2*)&wdst[hh * D_ + d2 * 2];
        as += xr[t][0] * ws.x + xr[t][1] * ws.y;
        ad += xr[t][0] * wd.x + xr[t][1] * wd.y;
      }
    }
#pragma unroll
    for (int off = 32; off; off >>= 1) { as += __shfl_down(as, off); ad += __shfl_down(ad, off); }
    if (lane == 0) { a_src[(size_t)row * H_ + hh] = as; a_dst[(size_t)row * H_ + hh] = ad; }
  }
}

// ---------------- pack A: (M x 300, T) -> (M x KP, bf16, zero-padded) ----------------
template <typename T>
__global__ void k_packA(const T* __restrict__ src, bf16* __restrict__ Ap, int M) {
  int idx = blockIdx.x * 256 + threadIdx.x;
  if (idx >= M * KP) return;
  int m = idx / KP, k = idx - m * KP;
  Ap[idx] = (k < D_) ? f2bf(toF(src[(size_t)m * D_ + k])) : f2bf(0.f);
}

// ---------------- pack B: (300 x 1500, f32) -> transposed (NP x KP, bf16, zero-pad) ----------------
__global__ void k_packB(const float* __restrict__ B, bf16* __restrict__ Bp) {
  int idx = blockIdx.x * 256 + threadIdx.x;
  if (idx >= NP * KP) return;
  int j = idx / KP, k = idx - j * KP;
  float v = (k < D_ && j < H_ * D_) ? B[(size_t)k * (H_ * D_) + j] : 0.f;
  Bp[idx] = f2bf(v);
}

// ---------------- MFMA GEMM: Ap(M x KP) @ Bp^T(NP x KP) -> C(M x NP, bf16) ----------------
// XCD-locality swizzle: x = b&7 (XCD), j = b>>3; rowgroup = x + 8*(j/12), col = j%12.
// The 12 column-blocks of one A-row-group run consecutively on one XCD -> A-tile L2-hits;
// the full B pack (984 KB) goes L2-resident per XCD.
__global__ __launch_bounds__(256) void k_gemm_mfma(const bf16* __restrict__ Ap,
                                                   const bf16* __restrict__ Bp,
                                                   bf16* __restrict__ C, int M, int nrow) {
  __shared__ short As[128][40];   // rows m, k contiguous; +8 pad -> bank stride 20
  __shared__ short Bs[128][40];   // rows n, k contiguous
  int b = blockIdx.x;
  int xcd = b & 7, j = b >> 3;
  int rg = xcd + 8 * (j / 12);
  if (rg >= nrow) return;
  int m0 = rg * 128, n0 = (j % 12) * 128;
  int tid = threadIdx.x;
  int wave = tid >> 6, lane = tid & 63;
  int wr = (wave >> 1) * 64, wc = (wave & 1) * 64;
  f32x4 acc[4][4] = {};
  for (int k0 = 0; k0 < KP; k0 += 32) {
    // stage A tile: 128 rows x 32 k = 512 x 16B chunks
#pragma unroll
    for (int cc = 0; cc < 2; ++cc) {
      int c = tid + cc * 256;
      int m = c >> 2, ko = (c & 3) << 3;
      int row = m0 + m; if (row >= M) row = M - 1;
      *(uint4*)&As[m][ko] = *(const uint4*)(Ap + (size_t)row * KP + k0 + ko);
    }
#pragma unroll
    for (int cc = 0; cc < 2; ++cc) {
      int c = tid + cc * 256;
      int n = c >> 2, ko = (c & 3) << 3;
      *(uint4*)&Bs[n][ko] = *(const uint4*)(Bp + (size_t)(n0 + n) * KP + k0 + ko);
    }
    __syncthreads();
    int kq = (lane >> 4) << 3;
    short8 af[4], bfr[4];
#pragma unroll
    for (int i = 0; i < 4; ++i) af[i]  = *(const short8*)&As[wr + i * 16 + (lane & 15)][kq];
#pragma unroll
    for (int jj = 0; jj < 4; ++jj) bfr[jj] = *(const short8*)&Bs[wc + jj * 16 + (lane & 15)][kq];
#pragma unroll
    for (int i = 0; i < 4; ++i)
#pragma unroll
      for (int jj = 0; jj < 4; ++jj)
        acc[i][jj] = __builtin_amdgcn_mfma_f32_16x16x32_bf16(af[i], bfr[jj], acc[i][jj], 0, 0, 0);
    __syncthreads();
  }
  // epilogue: C/D layout col=lane&15, row=(lane>>4)*4+r
  int cl = lane & 15, rq = (lane >> 4) << 2;
#pragma unroll
  for (int i = 0; i < 4; ++i) {
#pragma unroll
    for (int jj = 0; jj < 4; ++jj) {
      int col = n0 + wc + jj * 16 + cl;
#pragma unroll
      for (int r = 0; r < 4; ++r) {
        int row = m0 + wr + i * 16 + rq + r;
        if (row < M) C[(size_t)row * NP + col] = f2bf(acc[i][jj][r]);
      }
    }
  }
}

// ---------------- fused GAT aggregation + bias + relu + LayerNorm (CSR, wave/node) ----
// Block = 256 threads = 4 waves, each wave one node. No __syncthreads at all.
// h rows have stride NP; head hh at column hh*D_. In-place safe w.r.t. layer input.
__global__ __launch_bounds__(256) void k_agg_ln(
    const bf16* __restrict__ h, const float* __restrict__ a_src, const float* __restrict__ a_dst,
    const int* __restrict__ rowptr, int rstride,
    const int* __restrict__ col, int cstride,
    int nodes, int lbpg, int swz, int gs,
    const void* __restrict__ gmask, const int* __restrict__ mmode, int g_off,
    const float* __restrict__ bias, const float* __restrict__ g_ln, const float* __restrict__ b_ln,
    bf16* __restrict__ xout) {
  int b = blockIdx.x;
  int wv = threadIdx.x >> 6, lane = threadIdx.x & 63;
  int g, nb;
  if (swz) { int j = b >> 3; g = (b & 7) + ((j >> lbpg) << 3); nb = j & ((1 << lbpg) - 1); }
  else     { g = b >> lbpg; nb = b & ((1 << lbpg) - 1); }
  int node = (nb << 2) + wv;
  if (g >= gs || node >= nodes) return;
  int gg = g_off + g;
  const int* rp = rowptr + (size_t)gg * rstride;
  int r0 = rp[node];
  int deg = rp[node + 1] - r0;
  if (deg > MAXDEG) deg = MAXDEG;
  const int* cp = col + (size_t)gg * cstride + r0;
  int row0 = g * nodes;
  const float* adr = a_dst + (size_t)(row0 + node) * H_;
  float ad[H_];
#pragma unroll
  for (int hh = 0; hh < H_; ++hh) ad[hh] = adr[hh];
  int d0 = deg < 64 ? deg : 64;
  int s0 = 0; float l0[H_];
  if (lane < d0) {
    s0 = cp[lane];
    const float* ap = a_src + (size_t)(row0 + s0) * H_;
#pragma unroll
    for (int hh = 0; hh < H_; ++hh) { float v = ap[hh] + ad[hh]; l0[hh] = v > 0.f ? v : 0.2f * v; }
  } else {
#pragma unroll
    for (int hh = 0; hh < H_; ++hh) l0[hh] = -INFINITY;
  }
  bool two = deg > 64;
  int s1 = 0; float l1[H_];
#pragma unroll
  for (int hh = 0; hh < H_; ++hh) l1[hh] = -INFINITY;
  if (two && lane < deg - 64) {
    s1 = cp[64 + lane];
    const float* ap = a_src + (size_t)(row0 + s1) * H_;
#pragma unroll
    for (int hh = 0; hh < H_; ++hh) { float v = ap[hh] + ad[hh]; l1[hh] = v > 0.f ? v : 0.2f * v; }
  }
  float al0[H_], al1[H_];
#pragma unroll
  for (int hh = 0; hh < H_; ++hh) {
    float m = two ? fmaxf(l0[hh], l1[hh]) : l0[hh];
    for (int off = 1; off < deg && off < 64; off <<= 1) m = fmaxf(m, __shfl_xor(m, off));
    m = __shfl(m, 0);
    float e0 = (lane < d0) ? __expf(l0[hh] - m) : 0.f;
    float e1 = (two && lane < deg - 64) ? __expf(l1[hh] - m) : 0.f;
    float s = e0 + e1;
    for (int off = 1; off < deg && off < 64; off <<= 1) s += __shfl_xor(s, off);
    s = __shfl(s, 0);
    float inv = 1.f / (s + 1e-16f);
    al0[hh] = e0 * inv;
    al1[hh] = e1 * inv;
  }
  // aggregation: lane owns bf16 pairs d2, d2+64, d2+128 (150 pairs = 300 dims)
  float acc[3][2] = {};
  const char* hb = (const char*)h;
  for (int i = 0; i < deg; ++i) {
    int si; float aw[H_];
    if (i < 64) {
      si = __shfl(s0, i);
#pragma unroll
      for (int hh = 0; hh < H_; ++hh) aw[hh] = __shfl(al0[hh], i);
    } else {
      si = __shfl(s1, i - 64);
#pragma unroll
      for (int hh = 0; hh < H_; ++hh) aw[hh] = __shfl(al1[hh], i - 64);
    }
    const char* rb = hb + (size_t)(row0 + si) * (NP * 2);
#pragma unroll
    for (int t = 0; t < 3; ++t) {
      int d2 = lane + 64 * t;
      if (d2 < 150) {
#pragma unroll
        for (int hh = 0; hh < H_; ++hh) {
          unsigned int u = *(const unsigned int*)(rb + hh * (D_ * 2) + d2 * 4);
          float lo = __uint_as_float(u << 16);
          float hi = __uint_as_float(u & 0xFFFF0000u);
          acc[t][0] += aw[hh] * lo;
          acc[t][1] += aw[hh] * hi;
        }
      }
    }
  }
  // bias + mask + relu + LayerNorm (wave reduction)
  int msk = gmask ? read_mask(gmask, gg, mmode[0]) : 0;
  float y[3][2];
  float ps = 0.f, pq = 0.f;
#pragma unroll
  for (int t = 0; t < 3; ++t) {
    int d2 = lane + 64 * t;
    float y0 = 0.f, y1 = 0.f;
    if (d2 < 150) {
      float2 bb = *(const float2*)&bias[d2 * 2];
      y0 = acc[t][0] * (1.f / H_) + bb.x;
      y1 = acc[t][1] * (1.f / H_) + bb.y;
      if (msk) { y0 = 0.f; y1 = 0.f; }
      y0 = fmaxf(y0, 0.f); y1 = fmaxf(y1, 0.f);
      ps += y0 + y1; pq += y0 * y0 + y1 * y1;
    }
    y[t][0] = y0; y[t][1] = y1;
  }
#pragma unroll
  for (int off = 1; off < 64; off <<= 1) { ps += __shfl_xor(ps, off); pq += __shfl_xor(pq, off); }
  float mu = ps * (1.f / 300.f);
  float var = pq * (1.f / 300.f) - mu * mu;
  var = fmaxf(var, 0.f);
  float rstd = rsqrtf(var + 1e-5f);
  char* orow = (char*)(xout + (size_t)(row0 + node) * D_);
#pragma unroll
  for (int t = 0; t < 3; ++t) {
    int d2 = lane + 64 * t;
    if (d2 < 150) {
      float2 gv = *(const float2*)&g_ln[d2 * 2];
      float2 bv = *(const float2*)&b_ln[d2 * 2];
      float o0 = (y[t][0] - mu) * rstd * gv.x + bv.x;
      float o1 = (y[t][1] - mu) * rstd * gv.y + bv.y;
      bf16 c0 = f2bf(o0), c1 = f2bf(o1);
      unsigned int u = ((unsigned int)*(unsigned short*)&c1 << 16) | (unsigned int)*(unsigned short*)&c0;
      *(unsigned int*)(orow + d2 * 4) = u;
    }
  }
}

// ---------------- final: out[n, k]=a1, out[n, K+k]=a2 (f32 out) ----------------
__global__ void k_out(const float* __restrict__ u1, const float* __restrict__ u2,
                      const float* __restrict__ v2, const bf16* __restrict__ v3,
                      float* __restrict__ out) {
  int idx = blockIdx.x * blockDim.y + threadIdx.y;
  if (idx >= NB * KK) return;
  int n = idx / KK, k = idx - n * KK;
  int lane = threadIdx.x;
  const float* ap = v2 + (size_t)idx * D_;
  const bf16* bp = v3 + (size_t)idx * D_;
  const float* u1p = u1 + n * D_;
  const float* u2p = u2 + n * D_;
  float a1 = 0.f, a2 = 0.f;
  for (int d = lane; d < D_; d += 64) { a1 += u1p[d] * ap[d]; a2 += u2p[d] * toF(bp[d]); }
#pragma unroll
  for (int off = 32; off; off >>= 1) { a1 += __shfl_down(a1, off); a2 += __shfl_down(a2, off); }
  if (lane == 0) {
    const float scale = 0.05773502691896258f;  // 1/sqrt(300)
    out[(size_t)n * 2 * KK + k] = a1 * scale;
    out[(size_t)n * 2 * KK + KK + k] = a2 * scale;
  }
}

extern "C" void kernel_launch(void* const* d_in, const int* in_sizes, int n_in,
                              void* d_out, int out_size, void* d_ws, size_t ws_size,
                              hipStream_t stream) {
  const float* t2    = (const float*)d_in[0];
  const float* v2    = (const float*)d_in[1];
  const float* score = (const float*)d_in[2];
  const int*   eidx  = (const int*)d_in[3];
  const void*  gmask = d_in[4];
  const void*  kpm   = d_in[5];
  const void*  npm   = d_in[6];
  const int*   iedge = (const int*)d_in[7];
  const float* txtW  = (const float*)d_in[8];
  const float* txtAs = (const float*)d_in[9];
  const float* txtAd = (const float*)d_in[10];
  const float* txtB  = (const float*)d_in[11];
  const float* imgW  = (const float*)d_in[12];
  const float* imgAs = (const float*)d_in[13];
  const float* imgAd = (const float*)d_in[14];
  const float* imgB  = (const float*)d_in[15];
  const float* w1    = (const float*)d_in[16];
  const float* b1    = (const float*)d_in[17];
  const float* w2    = (const float*)d_in[18];
  const float* b2    = (const float*)d_in[19];
  const float* lng   = (const float*)d_in[20];
  const float* lnb   = (const float*)d_in[21];
  float* out = (float*)d_out;

  char* ws = (char*)d_ws;
  size_t off = 0;
  auto alloc = [&](size_t bytes) -> char* {
    char* p = ws + off;
    off += (bytes + 511) & ~(size_t)511;
    return p;
  };
  int*   mmode = (int*)alloc(64);
  float* c     = (float*)alloc((size_t)NB * D_ * 4);
  float* u1    = (float*)alloc((size_t)NB * D_ * 4);
  float* u2    = (float*)alloc((size_t)NB * D_ * 4);
  float* lg1   = (float*)alloc((size_t)NB * LL * 4);
  float* lg2   = (float*)alloc((size_t)NB * (LL + 1) * 4);
  float* pa1   = (float*)alloc((size_t)NB * LL * 4);
  float* pa2   = (float*)alloc((size_t)NB * (LL + 1) * 4);
  float* cpart = (float*)alloc((size_t)4 * NB * D_ * 4);
  float* up1   = (float*)alloc((size_t)4 * NB * D_ * 4);
  float* up2   = (float*)alloc((size_t)4 * NB * D_ * 4);
  float* wsrc  = (float*)alloc((size_t)H_ * D_ * 4);
  float* wdst  = (float*)alloc((size_t)H_ * D_ * 4);
  float* asrc  = (float*)alloc((size_t)NB * LL * H_ * 4);
  float* adst  = (float*)alloc((size_t)NB * LL * H_ * 4);
  int*   trp   = (int*)alloc((size_t)NB * (LL + 1) * 4);
  int*   tcol  = (int*)alloc((size_t)NB * ETXT * 4);
  int*   irp   = (int*)alloc((size_t)(KK + 1) * 4);
  int*   icol  = (int*)alloc((size_t)EIMG * 4);
  bf16*  X     = (bf16*)alloc((size_t)NB * LL * D_ * 2);   // txt state (in-place across layers)
  bf16*  V     = (bf16*)alloc((size_t)NB * KK * D_ * 2);   // img state (in-place across layers)
  bf16*  Bp    = (bf16*)alloc((size_t)NP * KP * 2);        // packed/transposed weights
  size_t havail = (ws_size > off) ? (ws_size - off) : 0;
  char* hstart = ws + off;
  // per-graph: Ap (rows x KP bf16) + hbuf (rows x NP bf16)
  size_t per_g_txt = (size_t)LL * (KP + NP) * 2;
  int cg = (int)(havail / per_g_txt);
  if (cg < 1) cg = 1;
  if (cg > NB) cg = NB;
  size_t per_g_img = (size_t)KK * (KP + NP) * 2;
  int cgi = (int)(havail / per_g_img);
  if (cgi < 1) cgi = 1;
  if (cgi > NB) cgi = NB;

  dim3 b64x4(64, 4);

  k_detect<<<1, 256, 0, stream>>>((const unsigned int*)kpm, NB * LL / 4, mmode);

  // CSR build (edges identical across layers -> build once)
  k_csr<<<NB, 256, 0, stream>>>(eidx, 2 * ETXT, ETXT, LL, trp, LL + 1, tcol, ETXT);
  k_csr<<<1, 256, 0, stream>>>(iedge, 0, EIMG, KK, irp, 0, icol, 0);

  // phase 0: c, pa_token logits
  k_c_part<<<dim3(NB, 4), 1024, 0, stream>>>(t2, score, cpart);
  k_c_red<<<(NB * D_ + 255) / 256, 256, 0, stream>>>(cpart, c);
  k_logits_tok<<<(NB * LL + 3) / 4, b64x4, 0, stream>>>(t2, w1, b1, kpm, mmode, lg1, NB * LL);

  // text GAT (2 layers), chunked over graphs, in-place on X
  {
    bf16* Ap   = (bf16*)hstart;
    bf16* hbuf = (bf16*)(hstart + (size_t)cg * LL * KP * 2);
    for (int layer = 0; layer < 2; ++layer) {
      const float* W = txtW + (size_t)layer * D_ * H_ * D_;
      k_packB<<<(NP * KP + 255) / 256, 256, 0, stream>>>(W, Bp);
      k_wvec<<<(2 * H_ * D_ + 255) / 256, 256, 0, stream>>>(
          W, txtAs + layer * H_ * D_, txtAd + layer * H_ * D_, wsrc, wdst);
      for (int g0 = 0; g0 < NB; g0 += cg) {
        int gs = (cg < NB - g0) ? cg : (NB - g0);
        int M = gs * LL;
        bf16* Xout = X + (size_t)g0 * LL * D_;
        if (layer == 0) {
          const float* Xin = t2 + (size_t)g0 * LL * D_;
          k_packA<float><<<(M * KP + 255) / 256, 256, 0, stream>>>(Xin, Ap, M);
          k_asrc<float><<<(M + 3) / 4, b64x4, 0, stream>>>(Xin, wsrc, wdst, asrc, adst, M);
        } else {
          const bf16* Xin = X + (size_t)g0 * LL * D_;
          k_packA<bf16><<<(M * KP + 255) / 256, 256, 0, stream>>>(Xin, Ap, M);
          k_asrc<bf16><<<(M + 3) / 4, b64x4, 0, stream>>>(Xin, wsrc, wdst, asrc, adst, M);
        }
        int nrow = (M + 127) / 128;
        k_gemm_mfma<<<12 * 8 * ((nrow + 7) / 8), 256, 0, stream>>>(Ap, Bp, hbuf, M, nrow);
        int swz = (gs % 8 == 0);
        k_agg_ln<<<gs * (LL / 4), 256, 0, stream>>>(hbuf, asrc, adst, trp, LL + 1, tcol, ETXT,
                                                    LL, 8, swz, gs, gmask, mmode, g0,
                                                    txtB + layer * D_, lng, lnb, Xout);
      }
    }
  }

  // image GAT (2 layers), shared edges, no gnn_mask, in-place on V
  {
    bf16* Ap   = (bf16*)hstart;
    bf16* hbuf = (bf16*)(hstart + (size_t)cgi * KK * KP * 2);
    for (int layer = 0; layer < 2; ++layer) {
      const float* W = imgW + (size_t)layer * D_ * H_ * D_;
      k_packB<<<(NP * KP + 255) / 256, 256, 0, stream>>>(W, Bp);
      k_wvec<<<(2 * H_ * D_ + 255) / 256, 256, 0, stream>>>(
          W, imgAs + layer * H_ * D_, imgAd + layer * H_ * D_, wsrc, wdst);
      for (int g0 = 0; g0 < NB; g0 += cgi) {
        int gs = (cgi < NB - g0) ? cgi : (NB - g0);
        int M = gs * KK;
        bf16* Vout = V + (size_t)g0 * KK * D_;
        if (layer == 0) {
          const float* Vin = v2 + (size_t)g0 * KK * D_;
          k_packA<float><<<(M * KP + 255) / 256, 256, 0, stream>>>(Vin, Ap, M);
          k_asrc<float><<<(M + 3) / 4, b64x4, 0, stream>>>(Vin, wsrc, wdst, asrc, adst, M);
        } else {
          const bf16* Vin = V + (size_t)g0 * KK * D_;
          k_packA<bf16><<<(M * KP + 255) / 256, 256, 0, stream>>>(Vin, Ap, M);
          k_asrc<bf16><<<(M + 3) / 4, b64x4, 0, stream>>>(Vin, wsrc, wdst, asrc, adst, M);
        }
        int nrow = (M + 127) / 128;
        k_gemm_mfma<<<12 * 8 * ((nrow + 7) / 8), 256, 0, stream>>>(Ap, Bp, hbuf, M, nrow);
        int swz = (gs % 8 == 0);
        k_agg_ln<<<gs * (KK / 4), 256, 0, stream>>>(hbuf, asrc, adst, irp, 0, icol, 0,
                                                    KK, 4, swz, gs, nullptr, mmode, 0,
                                                    imgB + layer * D_, lng, lnb, Vout);
      }
    }
  }

  // epilogue: pa_np logits, both softmaxes, weighted sums, output
  k_logits_np<<<(NB * (LL + 1) + 3) / 4, b64x4, 0, stream>>>(X, c, w2, b2, npm, mmode, lg2);
  k_pa<<<128, 1024, 0, stream>>>(lg1, lg2, pa1, pa2);
  k_u1part<<<dim3(NB, 4), 1024, 0, stream>>>(pa1, t2, up1);
  k_u2part<<<dim3(NB, 4), 1024, 0, stream>>>(pa2, X, c, up2);
  k_ured<<<(NB * D_ + 255) / 256, 256, 0, stream>>>(up1, up2, u1, u2);
  k_out<<<(NB * KK + 3) / 4, b64x4, 0, stream>>>(u1, u2, v2, V, out);
}